// Round 11
// baseline (324.449 us; speedup 1.0000x reference)
//
#include <hip/hip_runtime.h>
#include <hip/hip_fp16.h>

#define SEQ    2048
#define DIN    2048
#define DOUT   2048
#define NH     32
#define NKV    8
#define HD     64
#define BB     2

typedef _Float16 half_t;
typedef __attribute__((ext_vector_type(8))) _Float16 half8;
typedef __attribute__((ext_vector_type(4))) _Float16 half4;
typedef __attribute__((ext_vector_type(2))) __fp16   fp16x2;
typedef __attribute__((ext_vector_type(4))) float    floatx4;

union H8U { half8 h; int u[4]; };
union H2I { fp16x2 h; int i; };

#if __has_builtin(__builtin_amdgcn_exp2f)
#define EXP2F(x) __builtin_amdgcn_exp2f(x)
#else
#define EXP2F(x) __expf((x) * 0.6931471805599453f)
#endif

// async 16B global->LDS (wave-uniform LDS base + lane*16)
__device__ __forceinline__ void gload16(void* l, const void* g) {
    __builtin_amdgcn_global_load_lds(
        (const __attribute__((address_space(1))) void*)g,
        (__attribute__((address_space(3))) void*)l, 16, 0, 0);
}

// ---------------------------------------------------------------- fused prep:
// one dispatch = cast x f32->f16 (blocks 0..8191) + 4 transpose-casts
// (Wq|Wk|Wv -> WqkvT [3072][2048], Wo -> WoT [2048][2048]).
__global__ __launch_bounds__(256) void prep(
    const float* __restrict__ x,
    const float* __restrict__ Wq, const float* __restrict__ Wk,
    const float* __restrict__ Wv, const float* __restrict__ Wo,
    half_t* __restrict__ xh, half_t* __restrict__ WqkvT, half_t* __restrict__ WoT)
{
    __shared__ float T[32][33];
    int bid = blockIdx.x;
    if (bid < 8192) {                       // cast x (4096*2048 f32, float4/thread)
        int i = bid * 256 + threadIdx.x;
        float4 v = ((const float4*)x)[i];
        half4 h;
        h[0] = (half_t)v.x; h[1] = (half_t)v.y; h[2] = (half_t)v.z; h[3] = (half_t)v.w;
        ((half4*)xh)[i] = h;
        return;
    }
    bid -= 8192;
    const float* in; half_t* out; int Nd, bx, by;
    if (bid < 4096)      {            in = Wq; out = WqkvT;                        Nd = 2048; bx = bid & 63; by = bid >> 6; }
    else if (bid < 5120) { bid -= 4096; in = Wk; out = WqkvT + (size_t)2048 * 2048; Nd = 512;  bx = bid & 15; by = bid >> 4; }
    else if (bid < 6144) { bid -= 5120; in = Wv; out = WqkvT + (size_t)2560 * 2048; Nd = 512;  bx = bid & 15; by = bid >> 4; }
    else                 { bid -= 6144; in = Wo; out = WoT;                         Nd = 2048; bx = bid & 63; by = bid >> 6; }
    const int Kd = 2048;
    int x0 = bx * 32, y0 = by * 32;
    int tx = threadIdx.x & 31, ty = threadIdx.x >> 5;
    #pragma unroll
    for (int j = 0; j < 4; j++)
        T[ty + j * 8][tx] = in[(size_t)(y0 + ty + j * 8) * Nd + x0 + tx];
    __syncthreads();
    #pragma unroll
    for (int j = 0; j < 4; j++)
        out[(size_t)(x0 + ty + j * 8) * Kd + y0 + tx] = (half_t)T[tx][ty + j * 8];
}

// ================================================================ 128x128 / BK=64 / 4-wave 2-phase GEMM core
// m97 structure, BK=64 (measured best at this shape: 84-86 us across
// R3/R4/R6/R9/R10; beats BK=32-dbuf, 8-phase x2, 64x128, XCD-chunk).
// LDS per operand: 2 k-subblocks of [64 pairrows][8 slots][8 halves] = 16 KB.
//   slot = ((row&1)*4 + kq) ^ (pairrow&7)  (conflict-free; measured 0).
__device__ __forceinline__ void gemm128_core(
    const half_t* __restrict__ A, const half_t* __restrict__ Bt,
    int m0, int n0, half_t* As, half_t* Bs, floatx4 (&acc)[4][4])
{
    const int tid = threadIdx.x, wave = tid >> 6, lane = tid & 63;
    const int quad = lane >> 4, l15 = lane & 15;
    const int wm = (wave >> 1) * 64, wn = (wave & 1) * 64;
    const int K = DIN;

    const half_t* pa[4]; const half_t* pb[4]; int ldso[4];
    #pragma unroll
    for (int is = 0; is < 4; is++) {
        int s  = is * 256 + tid;        // [0,1024) 8-half groups
        int kb = s >> 9, s1 = s & 511;  // k-subblock, intra
        int p  = s1 >> 3, sc = s1 & 7;
        int c  = sc ^ (p & 7);
        int row  = 2 * p + (c >> 2);
        int koff = kb * 32 + (c & 3) * 8;
        pa[is] = A  + (size_t)(m0 + row) * K + koff;
        pb[is] = Bt + (size_t)(n0 + row) * K + koff;
        ldso[is] = (is * 256 + wave * 64) * 8;
    }
    int aoff[4], boff[4];
    #pragma unroll
    for (int m = 0; m < 4; m++) {
        int r = wm + m * 16 + l15, p = r >> 1;
        aoff[m] = p * 64 + ((((r & 1) * 4 + quad) ^ (p & 7)) * 8);
        int rn = wn + m * 16 + l15, pn = rn >> 1;
        boff[m] = pn * 64 + ((((rn & 1) * 4 + quad) ^ (pn & 7)) * 8);
    }

    for (int k0 = 0; k0 < K; k0 += 64) {
        __syncthreads();                 // all waves done reading LDS
        #pragma unroll
        for (int is = 0; is < 4; is++) {
            gload16(As + ldso[is], pa[is] + k0);
            gload16(Bs + ldso[is], pb[is] + k0);
        }
        __syncthreads();                 // staging landed
        half8 af[4][2], bf[4][2];
        #pragma unroll
        for (int i = 0; i < 4; i++) {
            af[i][0] = *(const half8*)(As + aoff[i]);
            af[i][1] = *(const half8*)(As + 4096 + aoff[i]);
            bf[i][0] = *(const half8*)(Bs + boff[i]);
            bf[i][1] = *(const half8*)(Bs + 4096 + boff[i]);
        }
        #pragma unroll
        for (int i = 0; i < 4; i++)
            #pragma unroll
            for (int j = 0; j < 4; j++)
                #pragma unroll
                for (int ks = 0; ks < 2; ks++)
                    acc[i][j] = __builtin_amdgcn_mfma_f32_16x16x32_f16(af[i][ks], bf[j][ks], acc[i][j], 0, 0, 0);
    }
}

// ---------------------------------------------------------------- fused QKV GEMM + Q/K-RoPE + relayout
// C = xh[4096x2048] @ WqkvT[3072x2048]^T ; each wave's 64-col span = one head:
//   cols <2048  : RoPE + scale(0.125*log2e) -> Qh [b][h][s][64]  (attn-ready)
//   2048..2559  : RoPE                      -> Kh [b][g][s][64]
//   2560..3071  : transpose                 -> Vt [b][g][d][SEQ]
__global__ __launch_bounds__(256) void gemm_qkv(
    const half_t* __restrict__ A, const half_t* __restrict__ Bt,
    const float* __restrict__ cosb, const float* __restrict__ sinb,
    half_t* __restrict__ Qh, half_t* __restrict__ Kh, half_t* __restrict__ Vt)
{
    __shared__ half_t As[8192];
    __shared__ half_t Bs[8192];
    const int m0 = blockIdx.y * 128, n0 = blockIdx.x * 128;

    floatx4 acc[4][4] = {};
    gemm128_core(A, Bt, m0, n0, As, Bs, acc);

    const int tid = threadIdx.x, wave = tid >> 6, lane = tid & 63;
    const int quad = lane >> 4, l15 = lane & 15;
    const int wm = (wave >> 1) * 64, wn = (wave & 1) * 64;
    const int headg = (n0 + wn) >> 6;          // 0..47
    const int b = m0 >> 11;                    // block never straddles batch
    const int s_base = (m0 & 2047) + wm + quad * 4;

    if (headg < 32) {                          // Q: RoPE + softmax scale (log2-domain)
        const float sc = 0.125f * 1.44269504088896f;
        half_t* outp = Qh + (size_t)(b * NH + headg) * SEQ * 64;
        #pragma unroll
        for (int i = 0; i < 4; i++)
            #pragma unroll
            for (int r = 0; r < 4; r++) {
                int s = s_base + i * 16 + r;
                #pragma unroll
                for (int j = 0; j < 2; j++) {
                    int d = j * 16 + l15;
                    float x1 = acc[i][j][r], x2 = acc[i][j + 2][r];
                    float c1 = cosb[s * 64 + d],      s1 = sinb[s * 64 + d];
                    float c2 = cosb[s * 64 + d + 32], s2 = sinb[s * 64 + d + 32];
                    outp[(size_t)s * 64 + d]      = (half_t)((x1 * c1 - x2 * s1) * sc);
                    outp[(size_t)s * 64 + d + 32] = (half_t)((x2 * c2 + x1 * s2) * sc);
                }
            }
    } else if (headg < 40) {                   // K: RoPE
        half_t* outp = Kh + (size_t)(b * NKV + (headg - 32)) * SEQ * 64;
        #pragma unroll
        for (int i = 0; i < 4; i++)
            #pragma unroll
            for (int r = 0; r < 4; r++) {
                int s = s_base + i * 16 + r;
                #pragma unroll
                for (int j = 0; j < 2; j++) {
                    int d = j * 16 + l15;
                    float x1 = acc[i][j][r], x2 = acc[i][j + 2][r];
                    float c1 = cosb[s * 64 + d],      s1 = sinb[s * 64 + d];
                    float c2 = cosb[s * 64 + d + 32], s2 = sinb[s * 64 + d + 32];
                    outp[(size_t)s * 64 + d]      = (half_t)(x1 * c1 - x2 * s1);
                    outp[(size_t)s * 64 + d + 32] = (half_t)(x2 * c2 + x1 * s2);
                }
            }
    } else {                                   // V: transpose to [d][s]
        half_t* vtp = Vt + (size_t)(b * NKV + (headg - 40)) * 64 * SEQ;
        #pragma unroll
        for (int i = 0; i < 4; i++) {
            int s = s_base + i * 16;
            #pragma unroll
            for (int j = 0; j < 4; j++) {
                int d = j * 16 + l15;
                half4 hv;
                hv[0] = (half_t)acc[i][j][0];
                hv[1] = (half_t)acc[i][j][1];
                hv[2] = (half_t)acc[i][j][2];
                hv[3] = (half_t)acc[i][j][3];
                *(half4*)(vtp + (size_t)d * SEQ + s) = hv;
            }
        }
    }
}

// ---------------------------------------------------------------- output projection, f32 out (128^2, R4 config)
__global__ __launch_bounds__(256) void gemm_tn_f(
    const half_t* __restrict__ A, const half_t* __restrict__ Bt,
    float* __restrict__ C)
{
    __shared__ half_t As[8192];
    __shared__ half_t Bs[8192];
    const int m0 = blockIdx.y * 128, n0 = blockIdx.x * 128;

    floatx4 acc[4][4] = {};
    gemm128_core(A, Bt, m0, n0, As, Bs, acc);

    const int tid = threadIdx.x, wave = tid >> 6, lane = tid & 63;
    const int quad = lane >> 4, l15 = lane & 15;
    const int wm = (wave >> 1) * 64, wn = (wave & 1) * 64;
    #pragma unroll
    for (int i = 0; i < 4; i++) {
        int row = m0 + wm + i * 16 + quad * 4;
        #pragma unroll
        for (int j = 0; j < 4; j++) {
            int col = n0 + wn + j * 16 + l15;
            #pragma unroll
            for (int r = 0; r < 4; r++)
                C[(size_t)(row + r) * DOUT + col] = acc[i][j][r];
        }
    }
}

// ---------------------------------------------------------------- causal GQA flash attention (S^T layout)
// R4 version (best measured): 256 thr / 4 waves / 32 q per wave / QBLK=128,
// shuffle-based P redistribution, T13 defer-max, T5 setprio, LDS-staged
// double-buffered K/V (proven to be the latency pipeline, R5).
__global__ __launch_bounds__(256, 4) void attn(
    const half_t* __restrict__ Qh, const half_t* __restrict__ Kh,
    const half_t* __restrict__ Vt, half_t* __restrict__ ctx)
{
    __shared__ half_t Ks[2][4096];
    __shared__ half_t Vs[2][4096];

    const int tid = threadIdx.x, wave = tid >> 6, lane = tid & 63;
    const int quad = lane >> 4, l15 = lane & 15;
    const int bid = blockIdx.x;
    const int k  = bid >> 8;
    const int u  = bid & 255;
    const int q2 = u & 3;
    const int bh = u >> 2;
    const int qt = (k == 0) ? 15 - 2 * q2 : (k == 1) ? 2 * q2
                 : (k == 2) ? 14 - 2 * q2 : 2 * q2 + 1;
    const int b  = bh >> 5;
    const int h  = bh & 31;
    const int g  = h >> 2;
    const int q0 = qt * 128;
    const int wm = wave * 32;

    const half_t* kp = Kh + (size_t)(b * NKV + g) * SEQ * 64;
    const half_t* vp = Vt + (size_t)(b * NKV + g) * 64 * SEQ;

    // Q fragments: direct loads (RoPE + scale already applied by gemm_qkv)
    half8 qf[2][2];
    {
        const half_t* qpp = Qh + ((size_t)(b * NH + h) * SEQ + q0 + wm) * 64;
        #pragma unroll
        for (int mf = 0; mf < 2; mf++) {
            qf[mf][0] = *(const half8*)(qpp + (size_t)(mf * 16 + l15) * 64 + quad * 8);
            qf[mf][1] = *(const half8*)(qpp + (size_t)(mf * 16 + l15) * 64 + 32 + quad * 8);
        }
    }

    int koff[2], voff[2], lo[2];
    #pragma unroll
    for (int is = 0; is < 2; is++) {
        int s = is * 256 + tid;
        int p = s >> 3, c = (s & 7) ^ (p & 7);
        koff[is] = p * 64 + c * 8;
        voff[is] = p * SEQ + c * 8;
        lo[is]   = (is * 256 + wave * 64) * 8;
    }

    float m_i[2], l_i[2];
    m_i[0] = m_i[1] = -__builtin_inff();
    l_i[0] = l_i[1] = 0.f;
    floatx4 o[2][4] = {};

    const int ntiles = 2 * qt + 2;
    #pragma unroll
    for (int is = 0; is < 2; is++) {
        gload16(&Ks[0][lo[is]], kp + koff[is]);
        gload16(&Vs[0][lo[is]], vp + voff[is]);
    }

    const int srcA = l15 + ((quad & 1) ? 32 : 0);
    const int srcB = srcA + 16;
    const bool hiK = (quad >> 1) != 0;

    for (int kt = 0; kt < ntiles; kt++) {
        const int cur = kt & 1;
        const int kb  = kt * 64;
        __syncthreads();
        if (kt + 1 < ntiles) {
            const int kb2 = (kt + 1) * 64;
            #pragma unroll
            for (int is = 0; is < 2; is++) {
                gload16(&Ks[cur ^ 1][lo[is]], kp + (size_t)kb2 * 64 + koff[is]);
                gload16(&Vs[cur ^ 1][lo[is]], vp + kb2 + voff[is]);
            }
        }

        if (kb <= q0 + wm + 31) {
            // S^T = K @ Q^T : rows = keys, cols = queries
            floatx4 sa[2][4] = {};
            __builtin_amdgcn_s_setprio(1);
            #pragma unroll
            for (int kc = 0; kc < 2; kc++)
                #pragma unroll
                for (int kf = 0; kf < 4; kf++) {
                    int row = kf * 16 + l15;
                    int sc = ((kc * 4 + quad) ^ (row & 7));
                    half8 kfr = *(const half8*)&Ks[cur][row * 64 + sc * 8];
                    sa[0][kf] = __builtin_amdgcn_mfma_f32_16x16x32_f16(kfr, qf[0][kc], sa[0][kf], 0, 0, 0);
                    sa[1][kf] = __builtin_amdgcn_mfma_f32_16x16x32_f16(kfr, qf[1][kc], sa[1][kf], 0, 0, 0);
                }
            __builtin_amdgcn_s_setprio(0);

            if (kb + 63 > q0 + wm) {   // diagonal tile: mask key > query
                #pragma unroll
                for (int kf = 0; kf < 4; kf++)
                    #pragma unroll
                    for (int r2 = 0; r2 < 4; r2++) {
                        int key = kb + kf * 16 + quad * 4 + r2;
                        if (key > q0 + wm + l15)      sa[0][kf][r2] = -__builtin_inff();
                        if (key > q0 + wm + 16 + l15) sa[1][kf][r2] = -__builtin_inff();
                    }
            }

            int eh[2][4][2];   // packed half2 exp values
            #pragma unroll
            for (int mf = 0; mf < 2; mf++) {
                float mt = sa[mf][0][0];
                #pragma unroll
                for (int kf = 0; kf < 4; kf++)
                    #pragma unroll
                    for (int r2 = 0; r2 < 4; r2++) mt = fmaxf(mt, sa[mf][kf][r2]);
                mt = fmaxf(mt, __shfl_xor(mt, 16));
                mt = fmaxf(mt, __shfl_xor(mt, 32));
                // T13 defer-max: only rescale when the tile max grew past THR=8
                if (!__all(mt - m_i[mf] <= 8.0f)) {
                    float mn2 = fmaxf(m_i[mf], mt);
                    float a = EXP2F(m_i[mf] - mn2);
                    m_i[mf] = mn2;
                    l_i[mf] *= a;
                    #pragma unroll
                    for (int nf = 0; nf < 4; nf++)
                        #pragma unroll
                        for (int r2 = 0; r2 < 4; r2++) o[mf][nf][r2] *= a;
                }
                const float mn = m_i[mf];
                float rs = 0.f;
                #pragma unroll
                for (int kf = 0; kf < 4; kf++) {
                    float e0 = EXP2F(sa[mf][kf][0] - mn);
                    float e1 = EXP2F(sa[mf][kf][1] - mn);
                    float e2 = EXP2F(sa[mf][kf][2] - mn);
                    float e3 = EXP2F(sa[mf][kf][3] - mn);
                    rs += (e0 + e1) + (e2 + e3);
                    H2I p01, p23;
                    p01.h = __builtin_amdgcn_cvt_pkrtz(e0, e1);
                    p23.h = __builtin_amdgcn_cvt_pkrtz(e2, e3);
                    eh[mf][kf][0] = p01.i;
                    eh[mf][kf][1] = p23.i;
                }
                rs += __shfl_xor(rs, 16);
                rs += __shfl_xor(rs, 32);
                l_i[mf] += rs;
            }

            // O^T += V^T @ P^T  (P^T B-frag via in-register shuffles)
            #pragma unroll
            for (int kc = 0; kc < 2; kc++) {
                H8U pf[2];
                #pragma unroll
                for (int mf = 0; mf < 2; mf++) {
                    int a0 = __shfl(eh[mf][2 * kc][0],     srcA);
                    int a1 = __shfl(eh[mf][2 * kc][1],     srcA);
                    int b0 = __shfl(eh[mf][2 * kc + 1][0], srcA);
                    int b1 = __shfl(eh[mf][2 * kc + 1][1], srcA);
                    int c0 = __shfl(eh[mf][2 * kc][0],     srcB);
                    int c1 = __shfl(eh[mf][2 * kc][1],     srcB);
                    int d0 = __shfl(eh[mf][2 * kc + 1][0], srcB);
                    int d1 = __shfl(eh[mf][2 * kc + 1][1], srcB);
                    pf[mf].u[0] = hiK ? b0 : a0;
                    pf[mf].u[1] = hiK ? b1 : a1;
                    pf[mf].u[2] = hiK ? d0 : c0;
                    pf[mf].u[3] = hiK ? d1 : c1;
                }
                __builtin_amdgcn_s_setprio(1);
                #pragma unroll
                for (int nf = 0; nf < 4; nf++) {
                    int row = nf * 16 + l15;
                    int sc = ((kc * 4 + quad) ^ (row & 7));
                    half8 vf = *(const half8*)&Vs[cur][row * 64 + sc * 8];
                    o[0][nf] = __builtin_amdgcn_mfma_f32_16x16x32_f16(vf, pf[0].h, o[0][nf], 0, 0, 0);
                    o[1][nf] = __builtin_amdgcn_mfma_f32_16x16x32_f16(vf, pf[1].h, o[1][nf], 0, 0, 0);
                }
                __builtin_amdgcn_s_setprio(0);
            }
        }
    }

    // epilogue: O^T cols = queries; d = 16nf + 4quad + r -> half4 stores
    #pragma unroll
    for (int mf = 0; mf < 2; mf++) {
        float inv = 1.0f / l_i[mf];
        int s = q0 + wm + mf * 16 + l15;
        half_t* op = ctx + (size_t)(b * SEQ + s) * DOUT + h * 64 + quad * 4;
        #pragma unroll
        for (int nf = 0; nf < 4; nf++) {
            half4 hv;
            hv[0] = (half_t)(o[mf][nf][0] * inv);
            hv[1] = (half_t)(o[mf][nf][1] * inv);
            hv[2] = (half_t)(o[mf][nf][2] * inv);
            hv[3] = (half_t)(o[mf][nf][3] * inv);
            *(half4*)(op + nf * 16) = hv;
        }
    }
}

// ---------------------------------------------------------------- launch
extern "C" void kernel_launch(void* const* d_in, const int* in_sizes, int n_in,
                              void* d_out, int out_size, void* d_ws, size_t ws_size,
                              hipStream_t stream) {
    const float* x    = (const float*)d_in[0];
    const float* cosb = (const float*)d_in[1];
    const float* sinb = (const float*)d_in[2];
    const float* Wq   = (const float*)d_in[4];
    const float* Wk   = (const float*)d_in[5];
    const float* Wv   = (const float*)d_in[6];
    const float* Wo   = (const float*)d_in[7];
    float* out = (float*)d_out;

    const size_t M  = (size_t)BB * SEQ;   // 4096

    char* ws = (char*)d_ws;
    const size_t MB = 1048576;
    half_t* xh     = (half_t*)(ws);              // 16 MiB
    half_t* WqkvT  = (half_t*)(ws + 16 * MB);    // 12 MiB  [3072][2048]
    half_t* WoT    = (half_t*)(ws + 28 * MB);    //  8 MiB
    half_t* Qh     = (half_t*)(ws + 36 * MB);    // 16 MiB  [b][h][s][64] (RoPE'd + scaled)
    half_t* Kh     = (half_t*)(ws + 52 * MB);    //  4 MiB  [b][g][s][64] (RoPE'd)
    half_t* Vt     = (half_t*)(ws + 56 * MB);    //  4 MiB  [b][g][d][SEQ]
    half_t* ctxh   = (half_t*)(ws + 60 * MB);    // 16 MiB  [b][s][h*64]

    // fused cast + weight transposes (1 dispatch)
    prep<<<18432, 256, 0, stream>>>(x, Wq, Wk, Wv, Wo, xh, WqkvT, WoT);

    // fused QKV projection + Q/K-RoPE + relayout
    gemm_qkv<<<dim3(3072 / 128, M / 128), 256, 0, stream>>>(xh, WqkvT, cosb, sinb, Qh, Kh, Vt);

    // attention (R4 best-measured version)
    attn<<<BB * NH * (SEQ / 128), 256, 0, stream>>>(Qh, Kh, Vt, ctxh);

    // output projection (128^2, R4 config)
    gemm_tn_f<<<dim3(DOUT / 128, M / 128), 256, 0, stream>>>(ctxh, WoT, out);
}

// Round 12
// 313.065 us; speedup vs baseline: 1.0364x; 1.0364x over previous
//
#include <hip/hip_runtime.h>
#include <hip/hip_fp16.h>

#define SEQ    2048
#define DIN    2048
#define DOUT   2048
#define NH     32
#define NKV    8
#define HD     64
#define BB     2

typedef _Float16 half_t;
typedef __attribute__((ext_vector_type(8))) _Float16 half8;
typedef __attribute__((ext_vector_type(4))) _Float16 half4;
typedef __attribute__((ext_vector_type(2))) __fp16   fp16x2;
typedef __attribute__((ext_vector_type(4))) float    floatx4;

union H8U { half8 h; int u[4]; };
union H2I { fp16x2 h; int i; };

#if __has_builtin(__builtin_amdgcn_exp2f)
#define EXP2F(x) __builtin_amdgcn_exp2f(x)
#else
#define EXP2F(x) __expf((x) * 0.6931471805599453f)
#endif

// async 16B global->LDS (wave-uniform LDS base + lane*16)
__device__ __forceinline__ void gload16(void* l, const void* g) {
    __builtin_amdgcn_global_load_lds(
        (const __attribute__((address_space(1))) void*)g,
        (__attribute__((address_space(3))) void*)l, 16, 0, 0);
}

// ---------------------------------------------------------------- fused prep:
// one dispatch = cast x f32->f16 (blocks 0..8191) + 4 transpose-casts
// (Wq|Wk|Wv -> WqkvT [3072][2048], Wo -> WoT [2048][2048]).
__global__ __launch_bounds__(256) void prep(
    const float* __restrict__ x,
    const float* __restrict__ Wq, const float* __restrict__ Wk,
    const float* __restrict__ Wv, const float* __restrict__ Wo,
    half_t* __restrict__ xh, half_t* __restrict__ WqkvT, half_t* __restrict__ WoT)
{
    __shared__ float T[32][33];
    int bid = blockIdx.x;
    if (bid < 8192) {                       // cast x (4096*2048 f32, float4/thread)
        int i = bid * 256 + threadIdx.x;
        float4 v = ((const float4*)x)[i];
        half4 h;
        h[0] = (half_t)v.x; h[1] = (half_t)v.y; h[2] = (half_t)v.z; h[3] = (half_t)v.w;
        ((half4*)xh)[i] = h;
        return;
    }
    bid -= 8192;
    const float* in; half_t* out; int Nd, bx, by;
    if (bid < 4096)      {            in = Wq; out = WqkvT;                        Nd = 2048; bx = bid & 63; by = bid >> 6; }
    else if (bid < 5120) { bid -= 4096; in = Wk; out = WqkvT + (size_t)2048 * 2048; Nd = 512;  bx = bid & 15; by = bid >> 4; }
    else if (bid < 6144) { bid -= 5120; in = Wv; out = WqkvT + (size_t)2560 * 2048; Nd = 512;  bx = bid & 15; by = bid >> 4; }
    else                 { bid -= 6144; in = Wo; out = WoT;                         Nd = 2048; bx = bid & 63; by = bid >> 6; }
    const int Kd = 2048;
    int x0 = bx * 32, y0 = by * 32;
    int tx = threadIdx.x & 31, ty = threadIdx.x >> 5;
    #pragma unroll
    for (int j = 0; j < 4; j++)
        T[ty + j * 8][tx] = in[(size_t)(y0 + ty + j * 8) * Nd + x0 + tx];
    __syncthreads();
    #pragma unroll
    for (int j = 0; j < 4; j++)
        out[(size_t)(x0 + ty + j * 8) * Kd + y0 + tx] = (half_t)T[tx][ty + j * 8];
}

// ================================================================ 128x128 / BK=64 / 4-wave 2-phase GEMM core
// m97 structure, BK=64 (measured best at this shape: 84-86 us across
// R3/R4/R6/R9/R10/R11; beats BK=32-dbuf, 8-phase x2, 64x128, XCD-chunk).
// LDS per operand: 2 k-subblocks of [64 pairrows][8 slots][8 halves] = 16 KB.
//   slot = ((row&1)*4 + kq) ^ (pairrow&7)  (conflict-free; measured 0).
__device__ __forceinline__ void gemm128_core(
    const half_t* __restrict__ A, const half_t* __restrict__ Bt,
    int m0, int n0, half_t* As, half_t* Bs, floatx4 (&acc)[4][4])
{
    const int tid = threadIdx.x, wave = tid >> 6, lane = tid & 63;
    const int quad = lane >> 4, l15 = lane & 15;
    const int wm = (wave >> 1) * 64, wn = (wave & 1) * 64;
    const int K = DIN;

    const half_t* pa[4]; const half_t* pb[4]; int ldso[4];
    #pragma unroll
    for (int is = 0; is < 4; is++) {
        int s  = is * 256 + tid;        // [0,1024) 8-half groups
        int kb = s >> 9, s1 = s & 511;  // k-subblock, intra
        int p  = s1 >> 3, sc = s1 & 7;
        int c  = sc ^ (p & 7);
        int row  = 2 * p + (c >> 2);
        int koff = kb * 32 + (c & 3) * 8;
        pa[is] = A  + (size_t)(m0 + row) * K + koff;
        pb[is] = Bt + (size_t)(n0 + row) * K + koff;
        ldso[is] = (is * 256 + wave * 64) * 8;
    }
    int aoff[4], boff[4];
    #pragma unroll
    for (int m = 0; m < 4; m++) {
        int r = wm + m * 16 + l15, p = r >> 1;
        aoff[m] = p * 64 + ((((r & 1) * 4 + quad) ^ (p & 7)) * 8);
        int rn = wn + m * 16 + l15, pn = rn >> 1;
        boff[m] = pn * 64 + ((((rn & 1) * 4 + quad) ^ (pn & 7)) * 8);
    }

    for (int k0 = 0; k0 < K; k0 += 64) {
        __syncthreads();                 // all waves done reading LDS
        #pragma unroll
        for (int is = 0; is < 4; is++) {
            gload16(As + ldso[is], pa[is] + k0);
            gload16(Bs + ldso[is], pb[is] + k0);
        }
        __syncthreads();                 // staging landed
        half8 af[4][2], bf[4][2];
        #pragma unroll
        for (int i = 0; i < 4; i++) {
            af[i][0] = *(const half8*)(As + aoff[i]);
            af[i][1] = *(const half8*)(As + 4096 + aoff[i]);
            bf[i][0] = *(const half8*)(Bs + boff[i]);
            bf[i][1] = *(const half8*)(Bs + 4096 + boff[i]);
        }
        #pragma unroll
        for (int i = 0; i < 4; i++)
            #pragma unroll
            for (int j = 0; j < 4; j++)
                #pragma unroll
                for (int ks = 0; ks < 2; ks++)
                    acc[i][j] = __builtin_amdgcn_mfma_f32_16x16x32_f16(af[i][ks], bf[j][ks], acc[i][j], 0, 0, 0);
    }
}

// ---------------------------------------------------------------- fused QKV GEMM + Q/K-RoPE + relayout
// C = xh[4096x2048] @ WqkvT[3072x2048]^T ; each wave's 64-col span = one head:
//   cols <2048  : RoPE + scale(0.125*log2e) -> Qh [b][h][s][64]  (attn-ready)
//   2048..2559  : RoPE                      -> Kh [b][g][s][64]
//   2560..3071  : transpose                 -> Vt [b][g][d][SEQ]
__global__ __launch_bounds__(256) void gemm_qkv(
    const half_t* __restrict__ A, const half_t* __restrict__ Bt,
    const float* __restrict__ cosb, const float* __restrict__ sinb,
    half_t* __restrict__ Qh, half_t* __restrict__ Kh, half_t* __restrict__ Vt)
{
    __shared__ half_t As[8192];
    __shared__ half_t Bs[8192];
    const int m0 = blockIdx.y * 128, n0 = blockIdx.x * 128;

    floatx4 acc[4][4] = {};
    gemm128_core(A, Bt, m0, n0, As, Bs, acc);

    const int tid = threadIdx.x, wave = tid >> 6, lane = tid & 63;
    const int quad = lane >> 4, l15 = lane & 15;
    const int wm = (wave >> 1) * 64, wn = (wave & 1) * 64;
    const int headg = (n0 + wn) >> 6;          // 0..47
    const int b = m0 >> 11;                    // block never straddles batch
    const int s_base = (m0 & 2047) + wm + quad * 4;

    if (headg < 32) {                          // Q: RoPE + softmax scale (log2-domain)
        const float sc = 0.125f * 1.44269504088896f;
        half_t* outp = Qh + (size_t)(b * NH + headg) * SEQ * 64;
        #pragma unroll
        for (int i = 0; i < 4; i++)
            #pragma unroll
            for (int r = 0; r < 4; r++) {
                int s = s_base + i * 16 + r;
                #pragma unroll
                for (int j = 0; j < 2; j++) {
                    int d = j * 16 + l15;
                    float x1 = acc[i][j][r], x2 = acc[i][j + 2][r];
                    float c1 = cosb[s * 64 + d],      s1 = sinb[s * 64 + d];
                    float c2 = cosb[s * 64 + d + 32], s2 = sinb[s * 64 + d + 32];
                    outp[(size_t)s * 64 + d]      = (half_t)((x1 * c1 - x2 * s1) * sc);
                    outp[(size_t)s * 64 + d + 32] = (half_t)((x2 * c2 + x1 * s2) * sc);
                }
            }
    } else if (headg < 40) {                   // K: RoPE
        half_t* outp = Kh + (size_t)(b * NKV + (headg - 32)) * SEQ * 64;
        #pragma unroll
        for (int i = 0; i < 4; i++)
            #pragma unroll
            for (int r = 0; r < 4; r++) {
                int s = s_base + i * 16 + r;
                #pragma unroll
                for (int j = 0; j < 2; j++) {
                    int d = j * 16 + l15;
                    float x1 = acc[i][j][r], x2 = acc[i][j + 2][r];
                    float c1 = cosb[s * 64 + d],      s1 = sinb[s * 64 + d];
                    float c2 = cosb[s * 64 + d + 32], s2 = sinb[s * 64 + d + 32];
                    outp[(size_t)s * 64 + d]      = (half_t)(x1 * c1 - x2 * s1);
                    outp[(size_t)s * 64 + d + 32] = (half_t)(x2 * c2 + x1 * s2);
                }
            }
    } else {                                   // V: transpose to [d][s]
        half_t* vtp = Vt + (size_t)(b * NKV + (headg - 40)) * 64 * SEQ;
        #pragma unroll
        for (int i = 0; i < 4; i++) {
            int s = s_base + i * 16;
            #pragma unroll
            for (int j = 0; j < 4; j++) {
                int d = j * 16 + l15;
                half4 hv;
                hv[0] = (half_t)acc[i][j][0];
                hv[1] = (half_t)acc[i][j][1];
                hv[2] = (half_t)acc[i][j][2];
                hv[3] = (half_t)acc[i][j][3];
                *(half4*)(vtp + (size_t)d * SEQ + s) = hv;
            }
        }
    }
}

// ---------------------------------------------------------------- output projection, f32 out (128^2, R4 config)
__global__ __launch_bounds__(256) void gemm_tn_f(
    const half_t* __restrict__ A, const half_t* __restrict__ Bt,
    float* __restrict__ C)
{
    __shared__ half_t As[8192];
    __shared__ half_t Bs[8192];
    const int m0 = blockIdx.y * 128, n0 = blockIdx.x * 128;

    floatx4 acc[4][4] = {};
    gemm128_core(A, Bt, m0, n0, As, Bs, acc);

    const int tid = threadIdx.x, wave = tid >> 6, lane = tid & 63;
    const int quad = lane >> 4, l15 = lane & 15;
    const int wm = (wave >> 1) * 64, wn = (wave & 1) * 64;
    #pragma unroll
    for (int i = 0; i < 4; i++) {
        int row = m0 + wm + i * 16 + quad * 4;
        #pragma unroll
        for (int j = 0; j < 4; j++) {
            int col = n0 + wn + j * 16 + l15;
            #pragma unroll
            for (int r = 0; r < 4; r++)
                C[(size_t)(row + r) * DOUT + col] = acc[i][j][r];
        }
    }
}

// ---------------------------------------------------------------- causal GQA flash attention (S^T layout)
// R4 structure (best measured) with two softmax micro-opts:
//  (a) deferred l_i reduction: per-lane partial row-sums, reduced ONCE in the
//      epilogue (alpha is wave-uniform post-max-reduce, so partials scale
//      identically -> algebraically exact). Removes 2 shuffles + 2 serial
//      adds per mf per tile from the critical chain.
//  (b) tree-max (v_max3-fusible) for the per-lane 16-score reduce:
//      15-deep serial fmax chain -> 3-level tree.
__global__ __launch_bounds__(256, 4) void attn(
    const half_t* __restrict__ Qh, const half_t* __restrict__ Kh,
    const half_t* __restrict__ Vt, half_t* __restrict__ ctx)
{
    __shared__ half_t Ks[2][4096];
    __shared__ half_t Vs[2][4096];

    const int tid = threadIdx.x, wave = tid >> 6, lane = tid & 63;
    const int quad = lane >> 4, l15 = lane & 15;
    const int bid = blockIdx.x;
    const int k  = bid >> 8;
    const int u  = bid & 255;
    const int q2 = u & 3;
    const int bh = u >> 2;
    const int qt = (k == 0) ? 15 - 2 * q2 : (k == 1) ? 2 * q2
                 : (k == 2) ? 14 - 2 * q2 : 2 * q2 + 1;
    const int b  = bh >> 5;
    const int h  = bh & 31;
    const int g  = h >> 2;
    const int q0 = qt * 128;
    const int wm = wave * 32;

    const half_t* kp = Kh + (size_t)(b * NKV + g) * SEQ * 64;
    const half_t* vp = Vt + (size_t)(b * NKV + g) * 64 * SEQ;

    // Q fragments: direct loads (RoPE + scale already applied by gemm_qkv)
    half8 qf[2][2];
    {
        const half_t* qpp = Qh + ((size_t)(b * NH + h) * SEQ + q0 + wm) * 64;
        #pragma unroll
        for (int mf = 0; mf < 2; mf++) {
            qf[mf][0] = *(const half8*)(qpp + (size_t)(mf * 16 + l15) * 64 + quad * 8);
            qf[mf][1] = *(const half8*)(qpp + (size_t)(mf * 16 + l15) * 64 + 32 + quad * 8);
        }
    }

    int koff[2], voff[2], lo[2];
    #pragma unroll
    for (int is = 0; is < 2; is++) {
        int s = is * 256 + tid;
        int p = s >> 3, c = (s & 7) ^ (p & 7);
        koff[is] = p * 64 + c * 8;
        voff[is] = p * SEQ + c * 8;
        lo[is]   = (is * 256 + wave * 64) * 8;
    }

    float m_i[2], l_i[2];          // l_i = PER-LANE partial row-sum (this lane's 16 keys/tile)
    m_i[0] = m_i[1] = -__builtin_inff();
    l_i[0] = l_i[1] = 0.f;
    floatx4 o[2][4] = {};

    const int ntiles = 2 * qt + 2;
    #pragma unroll
    for (int is = 0; is < 2; is++) {
        gload16(&Ks[0][lo[is]], kp + koff[is]);
        gload16(&Vs[0][lo[is]], vp + voff[is]);
    }

    const int srcA = l15 + ((quad & 1) ? 32 : 0);
    const int srcB = srcA + 16;
    const bool hiK = (quad >> 1) != 0;

    for (int kt = 0; kt < ntiles; kt++) {
        const int cur = kt & 1;
        const int kb  = kt * 64;
        __syncthreads();
        if (kt + 1 < ntiles) {
            const int kb2 = (kt + 1) * 64;
            #pragma unroll
            for (int is = 0; is < 2; is++) {
                gload16(&Ks[cur ^ 1][lo[is]], kp + (size_t)kb2 * 64 + koff[is]);
                gload16(&Vs[cur ^ 1][lo[is]], vp + kb2 + voff[is]);
            }
        }

        if (kb <= q0 + wm + 31) {
            // S^T = K @ Q^T : rows = keys, cols = queries
            floatx4 sa[2][4] = {};
            __builtin_amdgcn_s_setprio(1);
            #pragma unroll
            for (int kc = 0; kc < 2; kc++)
                #pragma unroll
                for (int kf = 0; kf < 4; kf++) {
                    int row = kf * 16 + l15;
                    int sc = ((kc * 4 + quad) ^ (row & 7));
                    half8 kfr = *(const half8*)&Ks[cur][row * 64 + sc * 8];
                    sa[0][kf] = __builtin_amdgcn_mfma_f32_16x16x32_f16(kfr, qf[0][kc], sa[0][kf], 0, 0, 0);
                    sa[1][kf] = __builtin_amdgcn_mfma_f32_16x16x32_f16(kfr, qf[1][kc], sa[1][kf], 0, 0, 0);
                }
            __builtin_amdgcn_s_setprio(0);

            if (kb + 63 > q0 + wm) {   // diagonal tile: mask key > query
                #pragma unroll
                for (int kf = 0; kf < 4; kf++)
                    #pragma unroll
                    for (int r2 = 0; r2 < 4; r2++) {
                        int key = kb + kf * 16 + quad * 4 + r2;
                        if (key > q0 + wm + l15)      sa[0][kf][r2] = -__builtin_inff();
                        if (key > q0 + wm + 16 + l15) sa[1][kf][r2] = -__builtin_inff();
                    }
            }

            int eh[2][4][2];   // packed half2 exp values
            #pragma unroll
            for (int mf = 0; mf < 2; mf++) {
                // (b) tree max over this lane's 16 scores (max3-fusible)
                float t0 = fmaxf(fmaxf(sa[mf][0][0], sa[mf][0][1]), fmaxf(sa[mf][0][2], sa[mf][0][3]));
                float t1 = fmaxf(fmaxf(sa[mf][1][0], sa[mf][1][1]), fmaxf(sa[mf][1][2], sa[mf][1][3]));
                float t2 = fmaxf(fmaxf(sa[mf][2][0], sa[mf][2][1]), fmaxf(sa[mf][2][2], sa[mf][2][3]));
                float t3 = fmaxf(fmaxf(sa[mf][3][0], sa[mf][3][1]), fmaxf(sa[mf][3][2], sa[mf][3][3]));
                float mt = fmaxf(fmaxf(t0, t1), fmaxf(t2, t3));
                mt = fmaxf(mt, __shfl_xor(mt, 16));
                mt = fmaxf(mt, __shfl_xor(mt, 32));
                // T13 defer-max: only rescale when the tile max grew past THR=8
                if (!__all(mt - m_i[mf] <= 8.0f)) {
                    float mn2 = fmaxf(m_i[mf], mt);
                    float a = EXP2F(m_i[mf] - mn2);
                    m_i[mf] = mn2;
                    l_i[mf] *= a;                  // per-lane partial scales uniformly
                    #pragma unroll
                    for (int nf = 0; nf < 4; nf++)
                        #pragma unroll
                        for (int r2 = 0; r2 < 4; r2++) o[mf][nf][r2] *= a;
                }
                const float mn = m_i[mf];
                float rs = 0.f;
                #pragma unroll
                for (int kf = 0; kf < 4; kf++) {
                    float e0 = EXP2F(sa[mf][kf][0] - mn);
                    float e1 = EXP2F(sa[mf][kf][1] - mn);
                    float e2 = EXP2F(sa[mf][kf][2] - mn);
                    float e3 = EXP2F(sa[mf][kf][3] - mn);
                    rs += (e0 + e1) + (e2 + e3);
                    H2I p01, p23;
                    p01.h = __builtin_amdgcn_cvt_pkrtz(e0, e1);
                    p23.h = __builtin_amdgcn_cvt_pkrtz(e2, e3);
                    eh[mf][kf][0] = p01.i;
                    eh[mf][kf][1] = p23.i;
                }
                // (a) deferred reduction: accumulate per-lane partial only
                l_i[mf] += rs;
            }

            // O^T += V^T @ P^T  (P^T B-frag via in-register shuffles)
            #pragma unroll
            for (int kc = 0; kc < 2; kc++) {
                H8U pf[2];
                #pragma unroll
                for (int mf = 0; mf < 2; mf++) {
                    int a0 = __shfl(eh[mf][2 * kc][0],     srcA);
                    int a1 = __shfl(eh[mf][2 * kc][1],     srcA);
                    int b0 = __shfl(eh[mf][2 * kc + 1][0], srcA);
                    int b1 = __shfl(eh[mf][2 * kc + 1][1], srcA);
                    int c0 = __shfl(eh[mf][2 * kc][0],     srcB);
                    int c1 = __shfl(eh[mf][2 * kc][1],     srcB);
                    int d0 = __shfl(eh[mf][2 * kc + 1][0], srcB);
                    int d1 = __shfl(eh[mf][2 * kc + 1][1], srcB);
                    pf[mf].u[0] = hiK ? b0 : a0;
                    pf[mf].u[1] = hiK ? b1 : a1;
                    pf[mf].u[2] = hiK ? d0 : c0;
                    pf[mf].u[3] = hiK ? d1 : c1;
                }
                __builtin_amdgcn_s_setprio(1);
                #pragma unroll
                for (int nf = 0; nf < 4; nf++) {
                    int row = nf * 16 + l15;
                    int sc = ((kc * 4 + quad) ^ (row & 7));
                    half8 vf = *(const half8*)&Vs[cur][row * 64 + sc * 8];
                    o[0][nf] = __builtin_amdgcn_mfma_f32_16x16x32_f16(vf, pf[0].h, o[0][nf], 0, 0, 0);
                    o[1][nf] = __builtin_amdgcn_mfma_f32_16x16x32_f16(vf, pf[1].h, o[1][nf], 0, 0, 0);
                }
                __builtin_amdgcn_s_setprio(0);
            }
        }
    }

    // epilogue: reduce the deferred row-sum once, then normalize + store
    #pragma unroll
    for (int mf = 0; mf < 2; mf++) {
        float lt = l_i[mf];
        lt += __shfl_xor(lt, 16);
        lt += __shfl_xor(lt, 32);
        float inv = 1.0f / lt;
        int s = q0 + wm + mf * 16 + l15;
        half_t* op = ctx + (size_t)(b * SEQ + s) * DOUT + h * 64 + quad * 4;
        #pragma unroll
        for (int nf = 0; nf < 4; nf++) {
            half4 hv;
            hv[0] = (half_t)(o[mf][nf][0] * inv);
            hv[1] = (half_t)(o[mf][nf][1] * inv);
            hv[2] = (half_t)(o[mf][nf][2] * inv);
            hv[3] = (half_t)(o[mf][nf][3] * inv);
            *(half4*)(op + nf * 16) = hv;
        }
    }
}

// ---------------------------------------------------------------- launch
extern "C" void kernel_launch(void* const* d_in, const int* in_sizes, int n_in,
                              void* d_out, int out_size, void* d_ws, size_t ws_size,
                              hipStream_t stream) {
    const float* x    = (const float*)d_in[0];
    const float* cosb = (const float*)d_in[1];
    const float* sinb = (const float*)d_in[2];
    const float* Wq   = (const float*)d_in[4];
    const float* Wk   = (const float*)d_in[5];
    const float* Wv   = (const float*)d_in[6];
    const float* Wo   = (const float*)d_in[7];
    float* out = (float*)d_out;

    const size_t M  = (size_t)BB * SEQ;   // 4096

    char* ws = (char*)d_ws;
    const size_t MB = 1048576;
    half_t* xh     = (half_t*)(ws);              // 16 MiB
    half_t* WqkvT  = (half_t*)(ws + 16 * MB);    // 12 MiB  [3072][2048]
    half_t* WoT    = (half_t*)(ws + 28 * MB);    //  8 MiB
    half_t* Qh     = (half_t*)(ws + 36 * MB);    // 16 MiB  [b][h][s][64] (RoPE'd + scaled)
    half_t* Kh     = (half_t*)(ws + 52 * MB);    //  4 MiB  [b][g][s][64] (RoPE'd)
    half_t* Vt     = (half_t*)(ws + 56 * MB);    //  4 MiB  [b][g][d][SEQ]
    half_t* ctxh   = (half_t*)(ws + 60 * MB);    // 16 MiB  [b][s][h*64]

    // fused cast + weight transposes (1 dispatch)
    prep<<<18432, 256, 0, stream>>>(x, Wq, Wk, Wv, Wo, xh, WqkvT, WoT);

    // fused QKV projection + Q/K-RoPE + relayout
    gemm_qkv<<<dim3(3072 / 128, M / 128), 256, 0, stream>>>(xh, WqkvT, cosb, sinb, Qh, Kh, Vt);

    // attention (R4 structure + deferred-l_i + tree-max)
    attn<<<BB * NH * (SEQ / 128), 256, 0, stream>>>(Qh, Kh, Vt, ctxh);

    // output projection (128^2, R4 config)
    gemm_tn_f<<<dim3(DOUT / 128, M / 128), 256, 0, stream>>>(ctxh, WoT, out);
}